// Round 3
// baseline (222.555 us; speedup 1.0000x reference)
//
#include <hip/hip_runtime.h>
#include <hip/hip_bf16.h>

#define NROWS 12288
#define DDIM  128
#define NT    96      // 12288/128 tiles per dimension
#define CHUNK 4       // j-tiles per block
#define NBLK  1200    // sum over bands bi of ceil((96-bi)/4)

typedef __bf16 bf16x8 __attribute__((ext_vector_type(8)));
typedef float  f32x4  __attribute__((ext_vector_type(4)));

// async global->LDS, 16B per lane; LDS dst is wave-uniform base + lane*16
#define GLD_LDS(g, l) __builtin_amdgcn_global_load_lds(                      \
    (const __attribute__((address_space(1))) void*)(g),                      \
    (__attribute__((address_space(3))) void*)(l), 16, 0, 0)

__device__ __forceinline__ unsigned short f2bf(float f) {
    union { float f; unsigned u; } a; a.f = f;
    unsigned r = a.u + 0x7fffu + ((a.u >> 16) & 1u);   // RNE to bf16
    return (unsigned short)(r >> 16);
}

__global__ void convert_kernel(const float* __restrict__ x, unsigned short* __restrict__ xb,
                               float* __restrict__ rowsum, float* __restrict__ out) {
    int gid = blockIdx.x * 256 + threadIdx.x;
    int i = gid * 4;
    float4 v = *(const float4*)(x + i);
    ushort4 o;
    o.x = f2bf(v.x); o.y = f2bf(v.y); o.z = f2bf(v.z); o.w = f2bf(v.w);
    *(ushort4*)(xb + i) = o;
    if (gid < NROWS) rowsum[gid] = 0.f;
    if (gid == 0) out[0] = 0.f;
}

// Stage one 128x128 bf16 tile into LDS, XOR-swizzled:
// LDS slot (row, s) holds global 16B-chunk (s ^ (row&7)) of row.
__device__ __forceinline__ void stage_tile(const unsigned short* __restrict__ xb,
                                           int row0, unsigned short* lds,
                                           int wave, int lane) {
    #pragma unroll
    for (int it = 0; it < 8; ++it) {
        int rbase = wave * 32 + it * 4;               // wave-uniform
        int r = rbase + (lane >> 4);
        int chunk = (lane & 15) ^ (r & 7);
        GLD_LDS(xb + (size_t)(row0 + r) * DDIM + chunk * 8, lds + rbase * DDIM);
    }
}

// One block per chunk of up-to-4 upper-triangular 128x128 tiles sharing a row band.
// A-fragments VGPR-resident for the whole strip (staged once through Bs overlay);
// B processed in 4 column-passes (acc[4] regs) to fit 128 VGPR @ 4 blocks/CU.
__global__ __launch_bounds__(256, 4) void gemm_exp_rowsum(
    const unsigned short* __restrict__ xb, float* __restrict__ rowsum)
{
    __shared__ __align__(16) unsigned short Bs[128 * DDIM];   // 32 KB (A overlay, then B tiles)
    __shared__ float csumS[CHUNK * 128];
    __shared__ float rsum[128];

    const int tid = threadIdx.x;

    // decode blockIdx -> (band bi, chunk start jt0)
    int rem = blockIdx.x, bi = 0;
    for (;;) {
        int nch = (NT - bi + CHUNK - 1) / CHUNK;
        if (rem < nch) break;
        rem -= nch; ++bi;
    }
    const int jt0 = bi + rem * CHUNK;
    const int ntiles = min(CHUNK, NT - jt0);
    const int i0 = bi * 128;

    for (int k = tid; k < CHUNK * 128; k += 256) csumS[k] = 0.f;
    if (tid < 128) rsum[tid] = 0.f;

    const int wave = tid >> 6, lane = tid & 63;
    const int wm = wave >> 1, wn = wave & 1;      // 2x2 waves, 64x64 each
    const int m16 = lane & 15, q = lane >> 4;

    // ---- stage A through Bs, pull fragments into VGPRs ----
    stage_tile(xb, i0, Bs, wave, lane);
    __syncthreads();                               // A DMA drained

    bf16x8 af[4][4];                               // [mi][ks] — 64 VGPRs, strip-resident
    #pragma unroll
    for (int mi = 0; mi < 4; ++mi) {
        int r = wm * 64 + mi * 16 + m16;
        #pragma unroll
        for (int ks = 0; ks < 4; ++ks)
            af[mi][ks] = *(const bf16x8*)(&Bs[r * DDIM + (((ks * 4 + q) ^ (r & 7)) * 8)]);
    }
    __syncthreads();                               // all waves done reading A from Bs

    stage_tile(xb, jt0 * 128, Bs, wave, lane);     // prologue: B_0 in flight

    const float C = 20.609929155556624f;           // (1/0.07) * log2(e) -> v_exp_f32 arg
    float rp[4][4];                                // row partials, whole strip
    #pragma unroll
    for (int mi = 0; mi < 4; ++mi)
        #pragma unroll
        for (int r = 0; r < 4; ++r) rp[mi][r] = 0.f;

    for (int t = 0; t < ntiles; ++t) {
        const int jt = jt0 + t;
        const bool offd = (jt != bi);
        __syncthreads();                           // B_t DMA drained, Bs ready

        f32x4 accL[4];                             // last pass kept for post-stage epilogue
        float cpL = 0.f;

        #pragma unroll
        for (int p = 0; p < 4; ++p) {
            const int br = wn * 64 + p * 16 + m16;
            const int bbase = br * DDIM;
            const int bsw = br & 7;

            f32x4 acc[4] = {};
            #pragma unroll
            for (int ks = 0; ks < 4; ++ks) {
                bf16x8 b = *(const bf16x8*)(&Bs[bbase + (((ks * 4 + q) ^ bsw) * 8)]);
                #pragma unroll
                for (int mi = 0; mi < 4; ++mi)
                    acc[mi] = __builtin_amdgcn_mfma_f32_16x16x32_bf16(af[mi][ks], b, acc[mi], 0, 0, 0);
            }

            if (p < 3) {
                // epilogue: C/D layout col = m16 (the j index), row = q*4 + r (the i index)
                float cp = 0.f;
                #pragma unroll
                for (int mi = 0; mi < 4; ++mi)
                    #pragma unroll
                    for (int r = 0; r < 4; ++r) {
                        float ev = __builtin_amdgcn_exp2f(acc[mi][r] * C);
                        rp[mi][r] += ev;
                        cp += ev;
                    }
                cp += __shfl_xor(cp, 16);
                cp += __shfl_xor(cp, 32);
                if (offd && q == 0) atomicAdd(&csumS[t * 128 + wn * 64 + p * 16 + m16], cp);
            } else {
                #pragma unroll
                for (int mi = 0; mi < 4; ++mi) accL[mi] = acc[mi];
            }
        }

        __syncthreads();                           // all Bs reads done -> buffer free
        if (t + 1 < ntiles) stage_tile(xb, (jt + 1) * 128, Bs, wave, lane);  // DMA flies...

        // ...while the last pass's exp epilogue runs (no LDS-Bs dependency)
        {
            float cp = 0.f;
            #pragma unroll
            for (int mi = 0; mi < 4; ++mi)
                #pragma unroll
                for (int r = 0; r < 4; ++r) {
                    float ev = __builtin_amdgcn_exp2f(accL[mi][r] * C);
                    rp[mi][r] += ev;
                    cp += ev;
                }
            cp += __shfl_xor(cp, 16);
            cp += __shfl_xor(cp, 32);
            if (offd && q == 0) atomicAdd(&csumS[t * 128 + wn * 64 + 3 * 16 + m16], cp);
        }
    }

    // row reduction: once per block
    #pragma unroll
    for (int mi = 0; mi < 4; ++mi)
        #pragma unroll
        for (int r = 0; r < 4; ++r) {
            float s = rp[mi][r];
            s += __shfl_xor(s, 1);
            s += __shfl_xor(s, 2);
            s += __shfl_xor(s, 4);
            s += __shfl_xor(s, 8);
            if (m16 == 0) atomicAdd(&rsum[wm * 64 + mi * 16 + q * 4 + r], s);
        }
    __syncthreads();

    if (tid < 128) atomicAdd(&rowsum[i0 + tid], rsum[tid]);
    for (int k = tid; k < ntiles * 128; k += 256) {
        float v = csumS[k];
        if (v != 0.f) atomicAdd(&rowsum[jt0 * 128 + k], v);
    }
}

__global__ void finalize_kernel(const float* __restrict__ rowsum, float* __restrict__ out) {
    __shared__ float red[4];
    int gid = blockIdx.x * 256 + threadIdx.x;
    float lg = __logf(rowsum[gid]);
    #pragma unroll
    for (int off = 1; off < 64; off <<= 1)
        lg += __shfl_xor(lg, off);
    const int wv = threadIdx.x >> 6, ln = threadIdx.x & 63;
    if (ln == 0) red[wv] = lg;
    __syncthreads();
    if (threadIdx.x == 0)
        atomicAdd(out, (red[0] + red[1] + red[2] + red[3]) * (1.0f / (float)NROWS));
}

extern "C" void kernel_launch(void* const* d_in, const int* in_sizes, int n_in,
                              void* d_out, int out_size, void* d_ws, size_t ws_size,
                              hipStream_t stream) {
    const float* x = (const float*)d_in[0];
    float* out = (float*)d_out;

    float* rowsum = (float*)d_ws;                                                 // 48 KB
    unsigned short* xb = (unsigned short*)((char*)d_ws + NROWS * sizeof(float));  // 3 MB bf16

    convert_kernel<<<dim3((NROWS * DDIM) / (4 * 256)), dim3(256), 0, stream>>>(x, xb, rowsum, out);
    gemm_exp_rowsum<<<dim3(NBLK), dim3(256), 0, stream>>>(xb, rowsum);
    finalize_kernel<<<dim3(NROWS / 256), dim3(256), 0, stream>>>(rowsum, out);
}

// Round 4
// 121.325 us; speedup vs baseline: 1.8344x; 1.8344x over previous
//
#include <hip/hip_runtime.h>
#include <hip/hip_bf16.h>

#define NROWS 12288
#define DDIM  128
#define NT    96      // 12288/128 tiles per dimension
#define CHUNK 4       // j-tiles per block
#define NBLK  1200    // sum over bands bi of ceil((96-bi)/4)

typedef __bf16 bf16x8 __attribute__((ext_vector_type(8)));
typedef float  f32x4  __attribute__((ext_vector_type(4)));

__device__ __forceinline__ unsigned short f2bf(float f) {
    union { float f; unsigned u; } a; a.f = f;
    unsigned r = a.u + 0x7fffu + ((a.u >> 16) & 1u);   // RNE to bf16
    return (unsigned short)(r >> 16);
}

__global__ void convert_kernel(const float* __restrict__ x, unsigned short* __restrict__ xb,
                               float* __restrict__ rowsum, float* __restrict__ out) {
    int gid = blockIdx.x * 256 + threadIdx.x;
    int i = gid * 4;
    float4 v = *(const float4*)(x + i);
    ushort4 o;
    o.x = f2bf(v.x); o.y = f2bf(v.y); o.z = f2bf(v.z); o.w = f2bf(v.w);
    *(ushort4*)(xb + i) = o;
    if (gid < NROWS) rowsum[gid] = 0.f;
    if (gid == 0) out[0] = 0.f;
}

// One block per chunk of up-to-4 upper-triangular 128x128 tiles in a row band.
// NO LDS tile staging: xb (3 MB bf16) is L2-resident; B fragments are read
// directly from global, interleaved with MFMA (compiler-scheduled vmcnt) —
// no barriers in the main loop. A fragments VGPR-resident for the strip.
// launch_bounds cap 3 waves/EU (~170 VGPRs): hard 128 cap caused total
// scratch spill in round 3 (VGPR=64, 334 MB scratch traffic) — leave slack.
__global__ __launch_bounds__(256, 3) void gemm_exp_rowsum(
    const unsigned short* __restrict__ xb, float* __restrict__ rowsum)
{
    __shared__ float csumS[CHUNK * 128];
    __shared__ float rsum[128];

    const int tid = threadIdx.x;

    // decode blockIdx -> (band bi, chunk start jt0)
    int rem = blockIdx.x, bi = 0;
    for (;;) {
        int nch = (NT - bi + CHUNK - 1) / CHUNK;
        if (rem < nch) break;
        rem -= nch; ++bi;
    }
    const int jt0 = bi + rem * CHUNK;
    const int ntiles = min(CHUNK, NT - jt0);
    const int i0 = bi * 128;

    for (int k = tid; k < CHUNK * 128; k += 256) csumS[k] = 0.f;
    if (tid < 128) rsum[tid] = 0.f;
    __syncthreads();   // zero-init visible before any LDS atomic

    const int wave = tid >> 6, lane = tid & 63;
    const int wm = wave >> 1, wn = wave & 1;      // 2x2 waves, 64x64 each
    const int m16 = lane & 15, q = lane >> 4;

    // A fragments straight from global (L2), once per strip: 64 VGPRs.
    bf16x8 af[4][4];
    #pragma unroll
    for (int mi = 0; mi < 4; ++mi) {
        const unsigned short* ap = xb + (size_t)(i0 + wm * 64 + mi * 16 + m16) * DDIM + q * 8;
        #pragma unroll
        for (int ks = 0; ks < 4; ++ks)
            af[mi][ks] = *(const bf16x8*)(ap + ks * 32);
    }

    const float C = 20.609929155556624f;          // (1/0.07) * log2(e) for v_exp_f32
    float rp[4][4];
    #pragma unroll
    for (int mi = 0; mi < 4; ++mi)
        #pragma unroll
        for (int r = 0; r < 4; ++r) rp[mi][r] = 0.f;

    for (int t = 0; t < ntiles; ++t) {
        const int jt = jt0 + t;
        const bool offd = (jt != bi);
        const unsigned short* bbase =
            xb + (size_t)(jt * 128 + wn * 64 + m16) * DDIM + q * 8;

        #pragma unroll
        for (int p = 0; p < 4; ++p) {
            // B rows jt*128 + wn*64 + p*16 + m16, direct from L2
            const unsigned short* bp = bbase + (size_t)(p * 16) * DDIM;
            bf16x8 bfr[4];
            #pragma unroll
            for (int ks = 0; ks < 4; ++ks)
                bfr[ks] = *(const bf16x8*)(bp + ks * 32);

            f32x4 acc[4] = {};
            #pragma unroll
            for (int ks = 0; ks < 4; ++ks)
                #pragma unroll
                for (int mi = 0; mi < 4; ++mi)
                    acc[mi] = __builtin_amdgcn_mfma_f32_16x16x32_bf16(
                        af[mi][ks], bfr[ks], acc[mi], 0, 0, 0);

            // C/D layout: col(j) = m16, row(i) = q*4 + r  [verified round 1]
            float cp = 0.f;
            #pragma unroll
            for (int mi = 0; mi < 4; ++mi)
                #pragma unroll
                for (int r = 0; r < 4; ++r) {
                    float ev = __builtin_amdgcn_exp2f(acc[mi][r] * C);
                    rp[mi][r] += ev;
                    cp += ev;
                }
            cp += __shfl_xor(cp, 16);
            cp += __shfl_xor(cp, 32);
            if (offd && q == 0)
                atomicAdd(&csumS[t * 128 + wn * 64 + p * 16 + m16], cp);
        }
    }

    // row reduction: once per block
    #pragma unroll
    for (int mi = 0; mi < 4; ++mi)
        #pragma unroll
        for (int r = 0; r < 4; ++r) {
            float s = rp[mi][r];
            s += __shfl_xor(s, 1);
            s += __shfl_xor(s, 2);
            s += __shfl_xor(s, 4);
            s += __shfl_xor(s, 8);
            if (m16 == 0) atomicAdd(&rsum[wm * 64 + mi * 16 + q * 4 + r], s);
        }
    __syncthreads();

    if (tid < 128) atomicAdd(&rowsum[i0 + tid], rsum[tid]);
    for (int k = tid; k < ntiles * 128; k += 256) {
        float v = csumS[k];
        if (v != 0.f) atomicAdd(&rowsum[jt0 * 128 + k], v);
    }
}

__global__ void finalize_kernel(const float* __restrict__ rowsum, float* __restrict__ out) {
    __shared__ float red[4];
    int gid = blockIdx.x * 256 + threadIdx.x;
    float lg = __logf(rowsum[gid]);
    #pragma unroll
    for (int off = 1; off < 64; off <<= 1)
        lg += __shfl_xor(lg, off);
    const int wv = threadIdx.x >> 6, ln = threadIdx.x & 63;
    if (ln == 0) red[wv] = lg;
    __syncthreads();
    if (threadIdx.x == 0)
        atomicAdd(out, (red[0] + red[1] + red[2] + red[3]) * (1.0f / (float)NROWS));
}

extern "C" void kernel_launch(void* const* d_in, const int* in_sizes, int n_in,
                              void* d_out, int out_size, void* d_ws, size_t ws_size,
                              hipStream_t stream) {
    const float* x = (const float*)d_in[0];
    float* out = (float*)d_out;

    float* rowsum = (float*)d_ws;                                                 // 48 KB
    unsigned short* xb = (unsigned short*)((char*)d_ws + NROWS * sizeof(float));  // 3 MB bf16

    convert_kernel<<<dim3((NROWS * DDIM) / (4 * 256)), dim3(256), 0, stream>>>(x, xb, rowsum, out);
    gemm_exp_rowsum<<<dim3(NBLK), dim3(256), 0, stream>>>(xb, rowsum);
    finalize_kernel<<<dim3(NROWS / 256), dim3(256), 0, stream>>>(rowsum, out);
}